// Round 1
// baseline (1089.962 us; speedup 1.0000x reference)
//
#include <hip/hip_runtime.h>

// SSIM loss, fused single pass + finalize.
// img1, img2: [64,1,512,512] fp32. Output: scalar fp32 = 1 - mean(ssim_map).
//
// Strategy: 5 channels (x, y, x^2, y^2, xy) box-filtered 11x11 with zero pad.
// Each thread owns an 8x8 output patch. 18 column-sums x 5 channels live in
// registers; vertical rolling update (add entering row, subtract leaving row),
// horizontal 11-tap sliding window. No global intermediates.

#define IMG_H 512
#define IMG_W 512
#define N_IMG 64

#define TXN 16   // threads in x
#define TYN 16   // threads in y
#define PC  8    // output cols per thread
#define PR  8    // output rows per thread
#define TILE_W (TXN * PC)   // 128
#define TILE_H (TYN * PR)   // 128
#define NC (PC + 10)        // 18 column sums per channel

__device__ __forceinline__ void accum_row(const float* __restrict__ row1,
                                          const float* __restrict__ row2,
                                          const int* cc, const float* cm,
                                          float* cs1, float* cs2,
                                          float* cs11, float* cs22, float* cs12,
                                          float sign) {
#pragma unroll
    for (int j = 0; j < NC; ++j) {
        float x = row1[cc[j]] * cm[j];
        float y = row2[cc[j]] * cm[j];
        float xs = x * sign;
        cs1[j] += xs;
        cs2[j] += y * sign;
        cs11[j] = fmaf(xs, x, cs11[j]);
        cs22[j] = fmaf(y * sign, y, cs22[j]);
        cs12[j] = fmaf(xs, y, cs12[j]);
    }
}

__global__ __launch_bounds__(256) void ssim_kernel(const float* __restrict__ img1,
                                                   const float* __restrict__ img2,
                                                   float* __restrict__ ws) {
    const int b = blockIdx.z;
    const int tx = threadIdx.x & (TXN - 1);
    const int ty = threadIdx.x / TXN;
    const int c0 = blockIdx.x * TILE_W + tx * PC;
    const int r0 = blockIdx.y * TILE_H + ty * PR;

    const float* __restrict__ p1 = img1 + (size_t)b * (IMG_H * IMG_W);
    const float* __restrict__ p2 = img2 + (size_t)b * (IMG_H * IMG_W);

    // Column clamp + {0,1} masks (columns fixed for the whole thread).
    int cc[NC];
    float cm[NC];
#pragma unroll
    for (int j = 0; j < NC; ++j) {
        int c = c0 - 5 + j;
        bool ok = (unsigned)c < (unsigned)IMG_W;
        cc[j] = ok ? c : 0;
        cm[j] = ok ? 1.0f : 0.0f;
    }

    float cs1[NC], cs2[NC], cs11[NC], cs22[NC], cs12[NC];
#pragma unroll
    for (int j = 0; j < NC; ++j) {
        cs1[j] = 0.f; cs2[j] = 0.f; cs11[j] = 0.f; cs22[j] = 0.f; cs12[j] = 0.f;
    }

    // Init column sums over rows r0-5 .. r0+5 (zero pad outside image).
#pragma unroll
    for (int dr = -5; dr <= 5; ++dr) {
        int r = r0 + dr;
        if ((unsigned)r < (unsigned)IMG_H) {
            const float* row1 = p1 + r * IMG_W;
            const float* row2 = p2 + r * IMG_W;
            accum_row(row1, row2, cc, cm, cs1, cs2, cs11, cs22, cs12, 1.0f);
        }
    }

    constexpr float inv = 1.0f / 121.0f;
    constexpr float c1 = 0.01f * 0.01f;
    constexpr float c2 = 0.03f * 0.03f;
    float acc = 0.0f;

#pragma unroll
    for (int rr = 0; rr < PR; ++rr) {
        const int r = r0 + rr;
        if (rr > 0) {
            int ri = r + 5;   // entering row
            int ro = r - 6;   // leaving row
            if (ri < IMG_H) {
                accum_row(p1 + ri * IMG_W, p2 + ri * IMG_W, cc, cm,
                          cs1, cs2, cs11, cs22, cs12, 1.0f);
            }
            if (ro >= 0) {
                accum_row(p1 + ro * IMG_W, p2 + ro * IMG_W, cc, cm,
                          cs1, cs2, cs11, cs22, cs12, -1.0f);
            }
        }

        // Horizontal 11-tap sliding window over column sums.
        float h1 = 0.f, h2 = 0.f, h11 = 0.f, h22 = 0.f, h12 = 0.f;
#pragma unroll
        for (int j = 0; j < 11; ++j) {
            h1 += cs1[j]; h2 += cs2[j]; h11 += cs11[j]; h22 += cs22[j]; h12 += cs12[j];
        }
#pragma unroll
        for (int k = 0; k < PC; ++k) {
            if (k > 0) {
                h1  += cs1[k + 10]  - cs1[k - 1];
                h2  += cs2[k + 10]  - cs2[k - 1];
                h11 += cs11[k + 10] - cs11[k - 1];
                h22 += cs22[k + 10] - cs22[k - 1];
                h12 += cs12[k + 10] - cs12[k - 1];
            }
            float mu1 = h1 * inv, mu2 = h2 * inv;
            float mu1mu2 = mu1 * mu2;
            float mu1sq = mu1 * mu1;
            float mu2sq = mu2 * mu2;
            float s12 = h12 * inv - mu1mu2;
            float s11 = h11 * inv - mu1sq;
            float s22 = h22 * inv - mu2sq;
            float num = (2.0f * mu1mu2 + c1) * (2.0f * s12 + c2);
            float den = (mu1sq + mu2sq + c1) * (s11 + s22 + c2);
            acc += __fdividef(num, den);
        }
    }

    // Reduce: wave (64) shuffle -> LDS -> one atomic per block.
#pragma unroll
    for (int off = 32; off > 0; off >>= 1) acc += __shfl_down(acc, off);

    __shared__ float wsum[4];
    const int lane = threadIdx.x & 63;
    const int wid = threadIdx.x >> 6;
    if (lane == 0) wsum[wid] = acc;
    __syncthreads();
    if (threadIdx.x == 0) {
        atomicAdd(ws, wsum[0] + wsum[1] + wsum[2] + wsum[3]);
    }
}

__global__ void ssim_finalize(const float* __restrict__ ws, float* __restrict__ out) {
    constexpr float inv_n = 1.0f / (float)((size_t)N_IMG * IMG_H * IMG_W);
    out[0] = 1.0f - ws[0] * inv_n;
}

extern "C" void kernel_launch(void* const* d_in, const int* in_sizes, int n_in,
                              void* d_out, int out_size, void* d_ws, size_t ws_size,
                              hipStream_t stream) {
    const float* img1 = (const float*)d_in[0];
    const float* img2 = (const float*)d_in[1];
    float* out = (float*)d_out;
    float* ws = (float*)d_ws;

    hipMemsetAsync(ws, 0, sizeof(float), stream);

    dim3 grid(IMG_W / TILE_W, IMG_H / TILE_H, N_IMG);  // (4, 4, 64)
    ssim_kernel<<<grid, TXN * TYN, 0, stream>>>(img1, img2, ws);
    ssim_finalize<<<1, 1, 0, stream>>>(ws, out);
}

// Round 2
// 203.762 us; speedup vs baseline: 5.3492x; 5.3492x over previous
//
#include <hip/hip_runtime.h>

// SSIM loss, fused: vertical rolling column-sums in registers (2 cols/thread,
// 10 regs of state), horizontal 11-tap via double-buffered LDS exchange.
// img1,img2: [64,1,512,512] fp32 -> scalar fp32 = 1 - mean(ssim_map).
//
// R1 post-mortem: 18-wide per-thread column halo spilled (VGPR=256, 1.86 GB
// scratch writes). This version keeps per-thread state at ~10 floats and
// shares column sums through LDS; all global loads stride-1 coalesced, all
// LDS accesses stride-1 across lanes (conflict-free).

#define IMG_H 512
#define IMG_W 512
#define N_IMG 64
#define STRIP 32
#define NTHREADS 256
#define LDSW (IMG_W + 10)   // 5 zero-pad each side

__global__ __launch_bounds__(NTHREADS) void ssim_kernel(const float* __restrict__ img1,
                                                        const float* __restrict__ img2,
                                                        float* __restrict__ ws) {
    __shared__ float V[2][5][LDSW];   // [buf][ch][padded col]; ch: x,y,xx,yy,xy
    const int t = threadIdx.x;
    const int b = blockIdx.y;
    const int r0 = blockIdx.x * STRIP;
    const float* __restrict__ p1 = img1 + (size_t)b * (IMG_H * IMG_W);
    const float* __restrict__ p2 = img2 + (size_t)b * (IMG_H * IMG_W);

    // Zero LDS once; pads (cols 0..4 and 517..521) stay zero forever.
    for (int i = t; i < 2 * 5 * LDSW; i += NTHREADS) (&V[0][0][0])[i] = 0.0f;

    const int c0 = t;
    const int c1 = t + NTHREADS;

    float cs[5][2];
#pragma unroll
    for (int ch = 0; ch < 5; ++ch) { cs[ch][0] = 0.f; cs[ch][1] = 0.f; }

    auto add_row = [&](int r) {
        const float* row1 = p1 + r * IMG_W;
        const float* row2 = p2 + r * IMG_W;
        float x0 = row1[c0], y0 = row2[c0];
        float x1 = row1[c1], y1 = row2[c1];
        cs[0][0] += x0;                       cs[0][1] += x1;
        cs[1][0] += y0;                       cs[1][1] += y1;
        cs[2][0] = fmaf(x0, x0, cs[2][0]);    cs[2][1] = fmaf(x1, x1, cs[2][1]);
        cs[3][0] = fmaf(y0, y0, cs[3][0]);    cs[3][1] = fmaf(y1, y1, cs[3][1]);
        cs[4][0] = fmaf(x0, y0, cs[4][0]);    cs[4][1] = fmaf(x1, y1, cs[4][1]);
    };
    auto sub_row = [&](int r) {
        const float* row1 = p1 + r * IMG_W;
        const float* row2 = p2 + r * IMG_W;
        float x0 = row1[c0], y0 = row2[c0];
        float x1 = row1[c1], y1 = row2[c1];
        cs[0][0] -= x0;                       cs[0][1] -= x1;
        cs[1][0] -= y0;                       cs[1][1] -= y1;
        cs[2][0] = fmaf(-x0, x0, cs[2][0]);   cs[2][1] = fmaf(-x1, x1, cs[2][1]);
        cs[3][0] = fmaf(-y0, y0, cs[3][0]);   cs[3][1] = fmaf(-y1, y1, cs[3][1]);
        cs[4][0] = fmaf(-x0, y0, cs[4][0]);   cs[4][1] = fmaf(-x1, y1, cs[4][1]);
    };

    // Warm the vertical window for output row r0 (zero pad outside image).
    {
        int rlo = r0 - 5; if (rlo < 0) rlo = 0;
        int rhi = r0 + 5; if (rhi > IMG_H - 1) rhi = IMG_H - 1;
        for (int r = rlo; r <= rhi; ++r) add_row(r);
    }

    __syncthreads();   // LDS zeroing complete before first buffer write

    constexpr float inv = 1.0f / 121.0f;
    constexpr float C1v = 0.01f * 0.01f;
    constexpr float C2v = 0.03f * 0.03f;
    float acc = 0.0f;

    for (int rr = 0; rr < STRIP; ++rr) {
        const int r = r0 + rr;
        if (rr > 0) {
            int ri = r + 5;
            int ro = r - 6;
            if (ri < IMG_H) add_row(ri);
            if (ro >= 0)    sub_row(ro);
        }

        float (*buf)[LDSW] = V[rr & 1];
#pragma unroll
        for (int ch = 0; ch < 5; ++ch) {
            buf[ch][5 + c0] = cs[ch][0];
            buf[ch][5 + c1] = cs[ch][1];
        }
        __syncthreads();

#pragma unroll
        for (int k = 0; k < 2; ++k) {
            const int c = (k == 0) ? c0 : c1;   // LDS idx c+j covers cols c-5..c+5
            float h[5];
#pragma unroll
            for (int ch = 0; ch < 5; ++ch) {
                float s = 0.f;
#pragma unroll
                for (int j = 0; j < 11; ++j) s += buf[ch][c + j];
                h[ch] = s;
            }
            float mu1 = h[0] * inv, mu2 = h[1] * inv;
            float mu1mu2 = mu1 * mu2, mu1sq = mu1 * mu1, mu2sq = mu2 * mu2;
            float s12 = fmaf(h[4], inv, -mu1mu2);
            float s11 = fmaf(h[2], inv, -mu1sq);
            float s22 = fmaf(h[3], inv, -mu2sq);
            float num = (2.f * mu1mu2 + C1v) * (2.f * s12 + C2v);
            float den = (mu1sq + mu2sq + C1v) * (s11 + s22 + C2v);
            acc += __fdividef(num, den);
        }
        // double buffer: next iteration writes the other half; one sync/iter
    }

    // Reduce: wave shuffle -> LDS -> one atomic per block.
#pragma unroll
    for (int off = 32; off > 0; off >>= 1) acc += __shfl_down(acc, off);
    __shared__ float wsum[4];
    if ((t & 63) == 0) wsum[t >> 6] = acc;
    __syncthreads();
    if (t == 0) atomicAdd(ws, wsum[0] + wsum[1] + wsum[2] + wsum[3]);
}

__global__ void ssim_finalize(const float* __restrict__ ws, float* __restrict__ out) {
    constexpr float inv_n = 1.0f / (float)((size_t)N_IMG * IMG_H * IMG_W);
    out[0] = 1.0f - ws[0] * inv_n;
}

extern "C" void kernel_launch(void* const* d_in, const int* in_sizes, int n_in,
                              void* d_out, int out_size, void* d_ws, size_t ws_size,
                              hipStream_t stream) {
    const float* img1 = (const float*)d_in[0];
    const float* img2 = (const float*)d_in[1];
    float* out = (float*)d_out;
    float* ws = (float*)d_ws;

    hipMemsetAsync(ws, 0, sizeof(float), stream);

    dim3 grid(IMG_H / STRIP, N_IMG);   // (16, 64) = 1024 blocks
    ssim_kernel<<<grid, NTHREADS, 0, stream>>>(img1, img2, ws);
    ssim_finalize<<<1, 1, 0, stream>>>(ws, out);
}